// Round 1
// baseline (207.964 us; speedup 1.0000x reference)
//
#include <hip/hip_runtime.h>

// One thread per atom. Computes the local-frame rotation matrix per the
// reference's axis_type state machine, then d = R^T * dipole, q = R^T * Q * R.
// rot rows are (x_vec, y_vec, z_vec); einsums contract over the ROW index.

__device__ __forceinline__ float3 nrm3(float ax, float ay, float az) {
    float s = ax * ax + ay * ay + az * az;
    float r = 1.0f / sqrtf(s);
    return make_float3(ax * r, ay * r, az * r);
}

__global__ __launch_bounds__(256) void mp_rot_kernel(
    const float* __restrict__ coords,
    const int* __restrict__ za,
    const int* __restrict__ xa,
    const int* __restrict__ ya,
    const int* __restrict__ at,
    const float* __restrict__ dip,
    const float* __restrict__ quad,
    float* __restrict__ out_d,
    float* __restrict__ out_q,
    int n)
{
    int i = blockIdx.x * blockDim.x + threadIdx.x;
    if (i >= n) return;

    int t = at[i];

    // Rotation matrix rows: R[0]=x_vec, R[1]=y_vec, R[2]=z_vec
    float R00, R01, R02, R10, R11, R12, R20, R21, R22;

    if (t == 5) {
        // 'na' type: identity frame; skip all gathers.
        R00 = 1.0f; R01 = 0.0f; R02 = 0.0f;
        R10 = 0.0f; R11 = 1.0f; R12 = 0.0f;
        R20 = 0.0f; R21 = 0.0f; R22 = 1.0f;
    } else {
        float cx = coords[3 * i + 0];
        float cy = coords[3 * i + 1];
        float cz = coords[3 * i + 2];

        int zi = za[i];
        float3 zv = nrm3(coords[3 * zi + 0] - cx,
                         coords[3 * zi + 1] - cy,
                         coords[3 * zi + 2] - cz);

        float3 xv;
        if (t == 4) {
            // fz_only: x = [1 - z0, z0, 0]
            xv = make_float3(1.0f - zv.x, zv.x, 0.0f);
        } else {
            int xi = xa[i];
            xv = nrm3(coords[3 * xi + 0] - cx,
                      coords[3 * xi + 1] - cy,
                      coords[3 * xi + 2] - cz);
        }

        if (t == 1) {
            // bisector
            zv = nrm3(zv.x + xv.x, zv.y + xv.y, zv.z + xv.z);
        }

        if (t == 2 || t == 3) {
            int yi = ya[i];
            float3 yn = nrm3(coords[3 * yi + 0] - cx,
                             coords[3 * yi + 1] - cy,
                             coords[3 * yi + 2] - cz);
            if (t == 2) {
                // z-bisector: x = norm(x + y_nb)
                xv = nrm3(xv.x + yn.x, xv.y + yn.y, xv.z + yn.z);
            } else {
                // trifurcated: z = norm(z + x + y_nb)
                zv = nrm3(zv.x + xv.x + yn.x, zv.y + xv.y + yn.y, zv.z + xv.z + yn.z);
            }
        }

        // Gram-Schmidt: x = norm(x - z * (z.x))
        float dzx = zv.x * xv.x + zv.y * xv.y + zv.z * xv.z;
        xv = nrm3(xv.x - zv.x * dzx, xv.y - zv.y * dzx, xv.z - zv.z * dzx);

        // y = cross(z, x)
        float3 yv = make_float3(zv.y * xv.z - zv.z * xv.y,
                                zv.z * xv.x - zv.x * xv.z,
                                zv.x * xv.y - zv.y * xv.x);

        R00 = xv.x; R01 = xv.y; R02 = xv.z;
        R10 = yv.x; R11 = yv.y; R12 = yv.z;
        R20 = zv.x; R21 = zv.y; R22 = zv.z;
    }

    // d[j] = sum_k dip[k] * R[k][j]
    float dp0 = dip[3 * i + 0];
    float dp1 = dip[3 * i + 1];
    float dp2 = dip[3 * i + 2];
    out_d[3 * i + 0] = dp0 * R00 + dp1 * R10 + dp2 * R20;
    out_d[3 * i + 1] = dp0 * R01 + dp1 * R11 + dp2 * R21;
    out_d[3 * i + 2] = dp0 * R02 + dp1 * R12 + dp2 * R22;

    // Q load
    float Q00 = quad[9 * i + 0], Q01 = quad[9 * i + 1], Q02 = quad[9 * i + 2];
    float Q10 = quad[9 * i + 3], Q11 = quad[9 * i + 4], Q12 = quad[9 * i + 5];
    float Q20 = quad[9 * i + 6], Q21 = quad[9 * i + 7], Q22 = quad[9 * i + 8];

    // M = R^T * Q : M[a][l] = sum_k R[k][a] * Q[k][l]
    float M00 = R00 * Q00 + R10 * Q10 + R20 * Q20;
    float M01 = R00 * Q01 + R10 * Q11 + R20 * Q21;
    float M02 = R00 * Q02 + R10 * Q12 + R20 * Q22;
    float M10 = R01 * Q00 + R11 * Q10 + R21 * Q20;
    float M11 = R01 * Q01 + R11 * Q11 + R21 * Q21;
    float M12 = R01 * Q02 + R11 * Q12 + R21 * Q22;
    float M20 = R02 * Q00 + R12 * Q10 + R22 * Q20;
    float M21 = R02 * Q01 + R12 * Q11 + R22 * Q21;
    float M22 = R02 * Q02 + R12 * Q12 + R22 * Q22;

    // O = M * R : O[a][b] = sum_l M[a][l] * R[l][b]
    out_q[9 * i + 0] = M00 * R00 + M01 * R10 + M02 * R20;
    out_q[9 * i + 1] = M00 * R01 + M01 * R11 + M02 * R21;
    out_q[9 * i + 2] = M00 * R02 + M01 * R12 + M02 * R22;
    out_q[9 * i + 3] = M10 * R00 + M11 * R10 + M12 * R20;
    out_q[9 * i + 4] = M10 * R01 + M11 * R11 + M12 * R21;
    out_q[9 * i + 5] = M10 * R02 + M11 * R12 + M12 * R22;
    out_q[9 * i + 6] = M20 * R00 + M21 * R10 + M22 * R20;
    out_q[9 * i + 7] = M20 * R01 + M21 * R11 + M22 * R21;
    out_q[9 * i + 8] = M20 * R02 + M21 * R12 + M22 * R22;
}

extern "C" void kernel_launch(void* const* d_in, const int* in_sizes, int n_in,
                              void* d_out, int out_size, void* d_ws, size_t ws_size,
                              hipStream_t stream) {
    const float* coords = (const float*)d_in[0];
    const int* za = (const int*)d_in[1];
    const int* xa = (const int*)d_in[2];
    const int* ya = (const int*)d_in[3];
    const int* at = (const int*)d_in[4];
    const float* dip = (const float*)d_in[5];
    const float* quad = (const float*)d_in[6];

    int n = in_sizes[1];  // z_atoms count == N
    float* out_d = (float*)d_out;
    float* out_q = out_d + (size_t)3 * n;

    int block = 256;
    int grid = (n + block - 1) / block;
    mp_rot_kernel<<<grid, block, 0, stream>>>(coords, za, xa, ya, at, dip, quad,
                                              out_d, out_q, n);
}